// Round 1
// baseline (474.937 us; speedup 1.0000x reference)
//
#include <hip/hip_runtime.h>
#include <hip/hip_bf16.h>

// Problem constants (fixed by setup_inputs): B=16, T=1024, D=256
#define BB 16
#define TT 1024
#define DD 256
// Tile: 64 (t) x 64 (s) per block, 256 threads = 4 waves, each wave a 16x64 strip.
#define BM 64
#define BN 64
#define LDK 264   // DD + 8 bf16 pad: row stride 528 B -> 2-way bank aliasing (free)

typedef __attribute__((ext_vector_type(4))) float f32x4;
typedef __bf16 bf16x8 __attribute__((ext_vector_type(8)));

__global__ void zero_ws_kernel(float* ws) {
    if (threadIdx.x < 2 * BB) ws[threadIdx.x] = 0.0f;
}

// accum layout in d_ws: [0..15] num per batch, [16..31] den per batch
__global__ __launch_bounds__(256, 2) void psl_main(
    const float* __restrict__ z, const float* __restrict__ gt,
    float* __restrict__ accum) {
    __shared__ __hip_bfloat16 As[BM * LDK];   // t-rows of z, bf16
    __shared__ __hip_bfloat16 Bs[BN * LDK];   // s-rows of z, bf16
    __shared__ float z2t[BM];
    __shared__ float z2s[BN];
    __shared__ float rbuf[8];

    const int tid  = threadIdx.x;
    const int lane = tid & 63;
    const int wv   = tid >> 6;
    const int b    = blockIdx.z;
    const int t0   = blockIdx.y * BM;
    const int s0   = blockIdx.x * BN;

    // ---- Stage z tiles (fp32 -> bf16) + per-row sum of squares (fp32) ----
    // Each pass: wave wv stages one full row (64 lanes x float4 = 256 floats).
    for (int half = 0; half < 2; ++half) {
        const int base       = half ? s0 : t0;
        __hip_bfloat16* dst  = half ? Bs : As;
        float* z2dst         = half ? z2s : z2t;
        for (int pass = 0; pass < 16; ++pass) {
            const int row = pass * 4 + wv;
            const f32x4 v = reinterpret_cast<const f32x4*>(
                z + ((size_t)b * TT + base + row) * DD)[lane];
            __hip_bfloat16 h0 = __float2bfloat16(v.x);
            __hip_bfloat16 h1 = __float2bfloat16(v.y);
            __hip_bfloat16 h2 = __float2bfloat16(v.z);
            __hip_bfloat16 h3 = __float2bfloat16(v.w);
            ushort4 pk;
            pk.x = *reinterpret_cast<const unsigned short*>(&h0);
            pk.y = *reinterpret_cast<const unsigned short*>(&h1);
            pk.z = *reinterpret_cast<const unsigned short*>(&h2);
            pk.w = *reinterpret_cast<const unsigned short*>(&h3);
            *reinterpret_cast<ushort4*>(&dst[row * LDK + lane * 4]) = pk;
            float ss = v.x * v.x + v.y * v.y + v.z * v.z + v.w * v.w;
            #pragma unroll
            for (int off = 32; off; off >>= 1) ss += __shfl_xor(ss, off);
            if (lane == 0) z2dst[row] = ss;
        }
    }
    __syncthreads();

    // ---- MFMA K-loop: G = Zt . Zs^T for this wave's 16x64 strip ----
    const int lane15 = lane & 15;
    const int quad   = lane >> 4;

    f32x4 acc[4];
    #pragma unroll
    for (int j = 0; j < 4; ++j) acc[j] = (f32x4){0.f, 0.f, 0.f, 0.f};

    const __hip_bfloat16* Abase = As + (wv * 16 + lane15) * LDK + quad * 8;
    const __hip_bfloat16* Bbase = Bs + lane15 * LDK + quad * 8;
    #pragma unroll
    for (int kk = 0; kk < 8; ++kk) {
        bf16x8 af = *reinterpret_cast<const bf16x8*>(Abase + kk * 32);
        #pragma unroll
        for (int j = 0; j < 4; ++j) {
            bf16x8 bfj = *reinterpret_cast<const bf16x8*>(Bbase + j * 16 * LDK + kk * 32);
            acc[j] = __builtin_amdgcn_mfma_f32_16x16x32_bf16(af, bfj, acc[j], 0, 0, 0);
        }
    }

    // ---- Epilogue: w = exp(-sum dT^2/(2 sigma^2)); accumulate num/den ----
    const float c_yx = 1.0f / (2.0f * 0.09f * 0.09f);
    const float c_hw = 1.0f / (2.0f * 0.3f * 0.3f);
    const int trow0 = wv * 16 + quad * 4;   // C layout: row = quad*4 + reg
    float z2t_r[4];
    #pragma unroll
    for (int i = 0; i < 4; ++i) z2t_r[i] = z2t[trow0 + i];

    float nsum = 0.0f, dsum = 0.0f;
    #pragma unroll
    for (int j = 0; j < 4; ++j) {
        const int s_loc = j * 16 + lane15;  // C layout: col = lane&15
        const float z2s_r = z2s[s_loc];
        const f32x4* gp = reinterpret_cast<const f32x4*>(gt)
                        + (((size_t)b * TT + t0 + trow0) * TT + s0 + s_loc);
        #pragma unroll
        for (int i = 0; i < 4; ++i) {
            const f32x4 dv = gp[(size_t)i * TT];
            const float e = (dv.x * dv.x + dv.y * dv.y) * c_yx
                          + (dv.z * dv.z + dv.w * dv.w) * c_hw;
            const float wgt = __expf(-e);
            nsum += wgt * (z2t_r[i] + z2s_r - 2.0f * acc[j][i]);
            dsum += wgt;
        }
    }

    // ---- Block reduction + global atomics ----
    #pragma unroll
    for (int off = 32; off; off >>= 1) {
        nsum += __shfl_xor(nsum, off);
        dsum += __shfl_xor(dsum, off);
    }
    if (lane == 0) { rbuf[wv] = nsum; rbuf[4 + wv] = dsum; }
    __syncthreads();
    if (tid == 0) {
        const float n = rbuf[0] + rbuf[1] + rbuf[2] + rbuf[3];
        const float d = rbuf[4] + rbuf[5] + rbuf[6] + rbuf[7];
        atomicAdd(&accum[b], n);
        atomicAdd(&accum[BB + b], d);
    }
}

__global__ void finalize_kernel(const float* __restrict__ accum,
                                float* __restrict__ out) {
    if (threadIdx.x == 0 && blockIdx.x == 0) {
        float s = 0.0f;
        for (int b = 0; b < BB; ++b)
            s += accum[b] / fmaxf(accum[BB + b], 1e-6f);
        out[0] = s / (float)BB;
    }
}

extern "C" void kernel_launch(void* const* d_in, const int* in_sizes, int n_in,
                              void* d_out, int out_size, void* d_ws, size_t ws_size,
                              hipStream_t stream) {
    const float* z  = (const float*)d_in[0];   // (B,T,D) fp32
    const float* gt = (const float*)d_in[1];   // (B,T,T,4) fp32
    float* out   = (float*)d_out;              // scalar fp32
    float* accum = (float*)d_ws;               // 32 floats

    zero_ws_kernel<<<1, 64, 0, stream>>>(accum);
    dim3 grid(TT / BN, TT / BM, BB);
    psl_main<<<grid, 256, 0, stream>>>(z, gt, accum);
    finalize_kernel<<<1, 64, 0, stream>>>(accum, out);
}

// Round 2
// 382.384 us; speedup vs baseline: 1.2420x; 1.2420x over previous
//
#include <hip/hip_runtime.h>
#include <hip/hip_bf16.h>

// Problem constants: B=16, T=1024, D=256
#define BB 16
#define TT 1024
#define DD 256
#define BM 64
#define BN 64
#define NGRP 64          // 16-row groups per batch (TT/16)
#define NKK 8            // K-chunks of 32 (DD/32)

typedef __attribute__((ext_vector_type(4))) float f32x4;
typedef __bf16 bf16x8 __attribute__((ext_vector_type(8)));
typedef unsigned short u16;
typedef u16 u16x8 __attribute__((ext_vector_type(8)));

// ws layout:
//   z_frag : offset 0,        16*64*8*64*8 u16 = 8388608 B
//   z2     : offset 8388608,  16*1024 f32 = 65536 B
//   accum  : offset 8454144,  32 f32 (num[16], den[16])
#define WS_Z2_OFF   8388608
#define WS_ACC_OFF  8454144

__global__ void zero_accum_kernel(float* acc) {
    if (threadIdx.x < 2 * BB) acc[threadIdx.x] = 0.0f;
}

// One wave per row: z2[r] = sum(z[r,:]^2). Grid: B*T/4 blocks of 256.
__global__ __launch_bounds__(256) void z2_kernel(
    const float* __restrict__ z, float* __restrict__ z2g) {
    const int lane = threadIdx.x & 63;
    const int wv   = threadIdx.x >> 6;
    const int row  = blockIdx.x * 4 + wv;          // flat b*T + t
    const f32x4 v = reinterpret_cast<const f32x4*>(z + (size_t)row * DD)[lane];
    float ss = v.x * v.x + v.y * v.y + v.z * v.z + v.w * v.w;
    #pragma unroll
    for (int off = 32; off; off >>= 1) ss += __shfl_xor(ss, off);
    if (lane == 0) z2g[row] = ss;
}

// One wave per (b, group, kk): emit the 16x32 bf16 fragment block in exact
// MFMA lane order. lane L holds z[b][g*16 + (L&15)][kk*32 + (L>>4)*8 + e].
// Grid: B*NGRP*NKK/4 blocks of 256.
__global__ __launch_bounds__(256) void frag_kernel(
    const float* __restrict__ z, u16* __restrict__ zf) {
    const int lane = threadIdx.x & 63;
    const int wv   = threadIdx.x >> 6;
    const int wid  = blockIdx.x * 4 + wv;          // 0 .. B*64*8-1
    const int b    = wid >> 9;
    const int rem  = wid & 511;
    const int g    = rem >> 3;
    const int kk   = rem & 7;
    const int lane15 = lane & 15;
    const int quad   = lane >> 4;

    const float* src = z + (((size_t)b * TT + g * 16 + lane15) * DD
                            + kk * 32 + quad * 8);
    const f32x4 v0 = reinterpret_cast<const f32x4*>(src)[0];
    const f32x4 v1 = reinterpret_cast<const f32x4*>(src)[1];
    float f[8] = {v0.x, v0.y, v0.z, v0.w, v1.x, v1.y, v1.z, v1.w};
    u16x8 pk;
    #pragma unroll
    for (int e = 0; e < 8; ++e) {
        __hip_bfloat16 h = __float2bfloat16(f[e]);
        pk[e] = *reinterpret_cast<const u16*>(&h);
    }
    reinterpret_cast<u16x8*>(zf)[(size_t)wid * 64 + lane] = pk;
}

// Main: 64x64 (t,s) tile per block, 4 waves each a 16x64 strip. No LDS
// staging — MFMA fragments load directly from z_frag (coalesced, L2/L3-hot).
__global__ __launch_bounds__(256, 4) void psl_main(
    const u16* __restrict__ zf, const float* __restrict__ z2g,
    const float* __restrict__ gt, float* __restrict__ accum) {
    __shared__ float rbuf[8];

    const int tid  = threadIdx.x;
    const int lane = tid & 63;
    const int wv   = tid >> 6;
    const int b    = blockIdx.z;
    const int t0   = blockIdx.y * BM;
    const int s0   = blockIdx.x * BN;
    const int lane15 = lane & 15;
    const int quad   = lane >> 4;

    const bf16x8* fragp = reinterpret_cast<const bf16x8*>(zf);
    const int gA = blockIdx.y * 4 + wv;            // this wave's t-group
    const int gB0 = blockIdx.x * 4;                // s-groups j=0..3

    // A fragments: 8 coalesced 16B/lane loads
    bf16x8 af[8];
    #pragma unroll
    for (int kk = 0; kk < NKK; ++kk)
        af[kk] = fragp[(((size_t)b * NGRP + gA) * NKK + kk) * 64 + lane];

    f32x4 acc[4];
    #pragma unroll
    for (int j = 0; j < 4; ++j) acc[j] = (f32x4){0.f, 0.f, 0.f, 0.f};

    #pragma unroll
    for (int j = 0; j < 4; ++j) {
        const size_t bbase = ((size_t)b * NGRP + gB0 + j) * NKK;
        #pragma unroll
        for (int kk = 0; kk < NKK; ++kk) {
            bf16x8 bfj = fragp[(bbase + kk) * 64 + lane];
            acc[j] = __builtin_amdgcn_mfma_f32_16x16x32_bf16(af[kk], bfj, acc[j], 0, 0, 0);
        }
    }

    // Epilogue: w = exp(-sum dT^2/(2 sigma^2)); accumulate num/den.
    const float c_yx = 1.0f / (2.0f * 0.09f * 0.09f);
    const float c_hw = 1.0f / (2.0f * 0.3f * 0.3f);
    const int trow0 = wv * 16 + quad * 4;          // C layout: row = quad*4 + reg
    float z2t_r[4];
    #pragma unroll
    for (int i = 0; i < 4; ++i) z2t_r[i] = z2g[b * TT + t0 + trow0 + i];

    float nsum = 0.0f, dsum = 0.0f;
    #pragma unroll
    for (int j = 0; j < 4; ++j) {
        const int s_loc = j * 16 + lane15;         // C layout: col = lane&15
        const float z2s_r = z2g[b * TT + s0 + s_loc];
        const f32x4* gp = reinterpret_cast<const f32x4*>(gt)
                        + (((size_t)b * TT + t0 + trow0) * TT + s0 + s_loc);
        #pragma unroll
        for (int i = 0; i < 4; ++i) {
            const f32x4 dv = gp[(size_t)i * TT];
            const float e = (dv.x * dv.x + dv.y * dv.y) * c_yx
                          + (dv.z * dv.z + dv.w * dv.w) * c_hw;
            const float wgt = __expf(-e);
            nsum += wgt * (z2t_r[i] + z2s_r - 2.0f * acc[j][i]);
            dsum += wgt;
        }
    }

    #pragma unroll
    for (int off = 32; off; off >>= 1) {
        nsum += __shfl_xor(nsum, off);
        dsum += __shfl_xor(dsum, off);
    }
    if (lane == 0) { rbuf[wv] = nsum; rbuf[4 + wv] = dsum; }
    __syncthreads();
    if (tid == 0) {
        const float n = rbuf[0] + rbuf[1] + rbuf[2] + rbuf[3];
        const float d = rbuf[4] + rbuf[5] + rbuf[6] + rbuf[7];
        atomicAdd(&accum[b], n);
        atomicAdd(&accum[BB + b], d);
    }
}

__global__ void finalize_kernel(const float* __restrict__ accum,
                                float* __restrict__ out) {
    if (threadIdx.x == 0 && blockIdx.x == 0) {
        float s = 0.0f;
        for (int b = 0; b < BB; ++b)
            s += accum[b] / fmaxf(accum[BB + b], 1e-6f);
        out[0] = s / (float)BB;
    }
}

extern "C" void kernel_launch(void* const* d_in, const int* in_sizes, int n_in,
                              void* d_out, int out_size, void* d_ws, size_t ws_size,
                              hipStream_t stream) {
    const float* z  = (const float*)d_in[0];   // (B,T,D) fp32
    const float* gt = (const float*)d_in[1];   // (B,T,T,4) fp32
    float* out = (float*)d_out;

    char* ws = (char*)d_ws;
    u16*   zf    = (u16*)ws;
    float* z2g   = (float*)(ws + WS_Z2_OFF);
    float* accum = (float*)(ws + WS_ACC_OFF);

    zero_accum_kernel<<<1, 64, 0, stream>>>(accum);
    z2_kernel<<<BB * TT / 4, 256, 0, stream>>>(z, z2g);
    frag_kernel<<<BB * NGRP * NKK / 4, 256, 0, stream>>>(z, zf);
    dim3 grid(TT / BN, TT / BM, BB);
    psl_main<<<grid, 256, 0, stream>>>(zf, z2g, gt, accum);
    finalize_kernel<<<1, 64, 0, stream>>>(accum, out);
}

// Round 3
// 380.532 us; speedup vs baseline: 1.2481x; 1.0049x over previous
//
#include <hip/hip_runtime.h>
#include <hip/hip_bf16.h>

// Problem constants: B=16, T=1024, D=256
#define BB 16
#define TT 1024
#define DD 256
#define BM 64
#define BN 64
#define NGRP 64          // 16-row groups per batch (TT/16)
#define NKK 8            // K-chunks of 32 (DD/32)

typedef __attribute__((ext_vector_type(4))) float f32x4;
typedef __bf16 bf16x8 __attribute__((ext_vector_type(8)));
typedef unsigned short u16;
typedef u16 u16x8 __attribute__((ext_vector_type(8)));

// ws layout:
//   z_frag : offset 0,        16*64*8*64*8 u16 = 8388608 B
//   z2     : offset 8388608,  16*1024 f32 = 65536 B
//   accum  : offset 8454144,  32 f32 (num[16], den[16])
#define WS_Z2_OFF   8388608
#define WS_ACC_OFF  8454144

// Async global->LDS DMA, 16 B/lane: lands at lds_base + lane*16.
#define GLD_LDS16(gp, lp) \
  __builtin_amdgcn_global_load_lds( \
      (const __attribute__((address_space(1))) void*)(gp), \
      (__attribute__((address_space(3))) void*)(lp), 16, 0, 0)

// One wave per row: z2[r] = sum(z[r,:]^2). Block 0 also zeroes the accums.
__global__ __launch_bounds__(256) void z2_kernel(
    const float* __restrict__ z, float* __restrict__ z2g,
    float* __restrict__ acc) {
    if (blockIdx.x == 0 && threadIdx.x < 2 * BB) acc[threadIdx.x] = 0.0f;
    const int lane = threadIdx.x & 63;
    const int wv   = threadIdx.x >> 6;
    const int row  = blockIdx.x * 4 + wv;          // flat b*T + t
    const f32x4 v = reinterpret_cast<const f32x4*>(z + (size_t)row * DD)[lane];
    float ss = v.x * v.x + v.y * v.y + v.z * v.z + v.w * v.w;
    #pragma unroll
    for (int off = 32; off; off >>= 1) ss += __shfl_xor(ss, off);
    if (lane == 0) z2g[row] = ss;
}

// One wave per (b, group, kk): emit the 16x32 bf16 fragment block in exact
// MFMA lane order. lane L holds z[b][g*16 + (L&15)][kk*32 + (L>>4)*8 + e].
__global__ __launch_bounds__(256) void frag_kernel(
    const float* __restrict__ z, u16* __restrict__ zf) {
    const int lane = threadIdx.x & 63;
    const int wv   = threadIdx.x >> 6;
    const int wid  = blockIdx.x * 4 + wv;          // 0 .. B*64*8-1
    const int b    = wid >> 9;
    const int rem  = wid & 511;
    const int g    = rem >> 3;
    const int kk   = rem & 7;
    const int lane15 = lane & 15;
    const int quad   = lane >> 4;

    const float* src = z + (((size_t)b * TT + g * 16 + lane15) * DD
                            + kk * 32 + quad * 8);
    const f32x4 v0 = reinterpret_cast<const f32x4*>(src)[0];
    const f32x4 v1 = reinterpret_cast<const f32x4*>(src)[1];
    float f[8] = {v0.x, v0.y, v0.z, v0.w, v1.x, v1.y, v1.z, v1.w};
    u16x8 pk;
    #pragma unroll
    for (int e = 0; e < 8; ++e) {
        __hip_bfloat16 h = __float2bfloat16(f[e]);
        pk[e] = *reinterpret_cast<const u16*>(&h);
    }
    reinterpret_cast<u16x8*>(zf)[(size_t)wid * 64 + lane] = pk;
}

// Main: 64x64 (t,s) tile per block, 4 waves each a 16x64 strip.
// Phase 0: DMA the block's 64KB gt tile into LDS (no VGPRs, vmcnt-tracked).
// Phase 1: MFMA Gram from fragment-ordered zf (L2-resident).
// Phase 2: barrier (drains DMA), epilogue reads gt from LDS.
__global__ __launch_bounds__(256, 2) void psl_main(
    const u16* __restrict__ zf, const float* __restrict__ z2g,
    const float* __restrict__ gt, float* __restrict__ accum) {
    __shared__ f32x4 gts[BM * BN];   // 64 KB gt tile, [row][col]
    __shared__ float rbuf[8];

    const int tid  = threadIdx.x;
    const int lane = tid & 63;
    const int wv   = tid >> 6;
    const int b    = blockIdx.z;
    const int t0   = blockIdx.y * BM;
    const int s0   = blockIdx.x * BN;
    const int lane15 = lane & 15;
    const int quad   = lane >> 4;

    // ---- Phase 0: issue gt tile DMA (wave wv covers local rows wv*16..+15)
    #pragma unroll
    for (int r16 = 0; r16 < 16; ++r16) {
        const int r = wv * 16 + r16;
        const float* gp = gt + ((((size_t)b * TT + t0 + r) * TT) + s0) * 4
                             + lane * 4;
        GLD_LDS16(gp, &gts[r * BN]);
    }

    // ---- Phase 1: MFMA Gram ----
    const bf16x8* fragp = reinterpret_cast<const bf16x8*>(zf);
    const int gA  = blockIdx.y * 4 + wv;           // this wave's t-group
    const int gB0 = blockIdx.x * 4;                // s-groups j=0..3

    bf16x8 af[NKK];
    #pragma unroll
    for (int kk = 0; kk < NKK; ++kk)
        af[kk] = fragp[(((size_t)b * NGRP + gA) * NKK + kk) * 64 + lane];

    f32x4 acc[4];
    #pragma unroll
    for (int j = 0; j < 4; ++j) acc[j] = (f32x4){0.f, 0.f, 0.f, 0.f};

    #pragma unroll
    for (int j = 0; j < 4; ++j) {
        const size_t bbase = ((size_t)b * NGRP + gB0 + j) * NKK;
        #pragma unroll
        for (int kk = 0; kk < NKK; ++kk) {
            bf16x8 bfj = fragp[(bbase + kk) * 64 + lane];
            acc[j] = __builtin_amdgcn_mfma_f32_16x16x32_bf16(af[kk], bfj, acc[j], 0, 0, 0);
        }
    }

    __syncthreads();   // drains vmcnt -> gt tile resident in LDS

    // ---- Phase 2: epilogue from LDS ----
    const float c_yx = 1.0f / (2.0f * 0.09f * 0.09f);
    const float c_hw = 1.0f / (2.0f * 0.3f * 0.3f);
    const int trow0 = wv * 16 + quad * 4;          // C layout: row = quad*4 + reg
    float z2t_r[4];
    #pragma unroll
    for (int i = 0; i < 4; ++i) z2t_r[i] = z2g[b * TT + t0 + trow0 + i];

    float nsum = 0.0f, dsum = 0.0f;
    #pragma unroll
    for (int j = 0; j < 4; ++j) {
        const int s_loc = j * 16 + lane15;         // C layout: col = lane&15
        const float z2s_r = z2g[b * TT + s0 + s_loc];
        #pragma unroll
        for (int i = 0; i < 4; ++i) {
            const f32x4 dv = gts[(trow0 + i) * BN + s_loc];
            const float e = (dv.x * dv.x + dv.y * dv.y) * c_yx
                          + (dv.z * dv.z + dv.w * dv.w) * c_hw;
            const float wgt = __expf(-e);
            nsum += wgt * (z2t_r[i] + z2s_r - 2.0f * acc[j][i]);
            dsum += wgt;
        }
    }

    #pragma unroll
    for (int off = 32; off; off >>= 1) {
        nsum += __shfl_xor(nsum, off);
        dsum += __shfl_xor(dsum, off);
    }
    if (lane == 0) { rbuf[wv] = nsum; rbuf[4 + wv] = dsum; }
    __syncthreads();
    if (tid == 0) {
        const float n = rbuf[0] + rbuf[1] + rbuf[2] + rbuf[3];
        const float d = rbuf[4] + rbuf[5] + rbuf[6] + rbuf[7];
        atomicAdd(&accum[b], n);
        atomicAdd(&accum[BB + b], d);
    }
}

__global__ void finalize_kernel(const float* __restrict__ accum,
                                float* __restrict__ out) {
    if (threadIdx.x == 0 && blockIdx.x == 0) {
        float s = 0.0f;
        for (int b = 0; b < BB; ++b)
            s += accum[b] / fmaxf(accum[BB + b], 1e-6f);
        out[0] = s / (float)BB;
    }
}

extern "C" void kernel_launch(void* const* d_in, const int* in_sizes, int n_in,
                              void* d_out, int out_size, void* d_ws, size_t ws_size,
                              hipStream_t stream) {
    const float* z  = (const float*)d_in[0];   // (B,T,D) fp32
    const float* gt = (const float*)d_in[1];   // (B,T,T,4) fp32
    float* out = (float*)d_out;

    char* ws = (char*)d_ws;
    u16*   zf    = (u16*)ws;
    float* z2g   = (float*)(ws + WS_Z2_OFF);
    float* accum = (float*)(ws + WS_ACC_OFF);

    z2_kernel<<<BB * TT / 4, 256, 0, stream>>>(z, z2g, accum);
    frag_kernel<<<BB * NGRP * NKK / 4, 256, 0, stream>>>(z, zf);
    dim3 grid(TT / BN, TT / BM, BB);
    psl_main<<<grid, 256, 0, stream>>>(zf, z2g, gt, accum);
    finalize_kernel<<<1, 64, 0, stream>>>(accum, out);
}